// Round 13
// baseline (109.539 us; speedup 1.0000x reference)
//
#include <hip/hip_runtime.h>
#include <cstdint>

#define B_   32
#define CIN  256
#define COUT 256
#define H_   56
#define W_   56
#define HP   58          // padded spatial dim (pad=1 each side)
#define HW   (H_ * W_)   // 3136

typedef int v4i  __attribute__((ext_vector_type(4)));
typedef int v16i __attribute__((ext_vector_type(16)));

// ==================================================================
// XNOR conv via i8 MFMA: a,w in {+1,-1}; zero-pad = i8 0 (exact).
// ==================================================================

// ---- pack_a8: NCHW fp32 -> padded NHWC i8. A8[b][hh][ww][ci] ----
__global__ __launch_bounds__(256) void pack_a8_kernel(
    const float* __restrict__ x, const float* __restrict__ alpha,
    char* __restrict__ A8) {
  const int w = threadIdx.x & 63;
  const int q = threadIdx.x >> 6;
  const int hh = blockIdx.x * 4 + q;
  const int b = blockIdx.y;
  if (hh >= HP) return;
  char* rowbase = A8 + (size_t)(b * HP + hh) * (HP * 256);
  const uint4 z = make_uint4(0u, 0u, 0u, 0u);
  if (hh == 0 || hh == HP - 1) {           // border row: all zeros
    for (int i = w; i < HP * 16; i += 64) *(uint4*)(rowbase + i * 16) = z;
    return;
  }
  const int h = hh - 1;
  if (w < W_) {
    char* dst = rowbase + (w + 1) * 256;
    const float* xp = x + (size_t)b * CIN * HW + h * W_ + w;
    for (int cw = 0; cw < 16; ++cw) {      // 16B of channels per iter
      uint32_t wd[4];
      #pragma unroll
      for (int u = 0; u < 4; ++u) {
        uint32_t word = 0;
        #pragma unroll
        for (int bb = 0; bb < 4; ++bb) {
          int c = cw * 16 + u * 4 + bb;
          float v = xp[(size_t)c * HW];
          word |= ((v > alpha[c]) ? 0x01u : 0xFFu) << (bb * 8);
        }
        wd[u] = word;
      }
      *(uint4*)(dst + cw * 16) = *(uint4*)wd;
    }
  } else if (w == 56 || w == 57) {         // border pixels ww=0 / ww=57
    char* dst = rowbase + ((w == 56) ? 0 : (HP - 1)) * 256;
    #pragma unroll
    for (int i = 0; i < 16; ++i) *(uint4*)(dst + i * 16) = z;
  }
}

// ---- pack_w8: W in exact B-fragment form (HW-verified, absmax 0) ----
// Wf[((tap*8 + kc)*8 + ng)*64 + lane]: co = ng*32 + (lane&31),
// ci = kc*32 + (lane>>5)*16 + byte j
__global__ __launch_bounds__(256) void pack_w8_kernel(
    const float* __restrict__ wt, v4i* __restrict__ Wf) {
  int id = blockIdx.x * 256 + threadIdx.x;   // 36864 total
  int lane = id & 63;
  int ng = (id >> 6) & 7;
  int kc = (id >> 9) & 7;
  int tap = id >> 12;
  if (tap >= 9) return;
  int kh = tap / 3, kw = tap - kh * 3;
  int co = ng * 32 + (lane & 31);
  int cib = kc * 32 + (lane >> 5) * 16;
  uint32_t wd[4];
  #pragma unroll
  for (int u = 0; u < 4; ++u) {
    uint32_t word = 0;
    #pragma unroll
    for (int bb = 0; bb < 4; ++bb) {
      int ci = cib + u * 4 + bb;
      float v = wt[((size_t)(co * CIN + ci) * 3 + kh) * 3 + kw];
      word |= ((v > 0.0f) ? 0x01u : 0xFFu) << (bb * 8);
    }
    wd[u] = word;
  }
  Wf[id] = *(v4i*)wd;
}

// ---- conv_mfma v10: M64xN32 waves -> 5 waves/SIMD ----
// Block: 256 thr / 4 waves. Block tile M64 (2 oh x 32 ow) x N128 (coh).
// Wave: M64 x N32 (ng = coh*4+wn); acc[2] v16i = 32 regs; est total ~85
// -> launch_bounds(256,5): 5 waves/SIMD, 5 blocks/CU (r12: duty ~15.8%
// x waves is the ONLY lever that has moved MfmaUtil; no pipe saturated).
// Slab per kc-phase: [gr8][rr4][ww34] x 16B = 17,408 B. Grid 3584
// (= 8x448 bijective XCD swizzle) -> pacing 5+5+4 (93% of capacity).
// Inner batch (kcp,kw): 4 af ds_reads (rr0..3) + 3 bf L2 loads + 6 MFMAs.
// Epilogue: r10's proven per-ohl stride-144 transpose (conflict-free).
__global__ __launch_bounds__(256, 5) void conv_mfma_kernel(
    const char* __restrict__ A8, const v4i* __restrict__ Wf,
    float* __restrict__ out) {
  __shared__ alignas(16) char lds[18432];   // slab 17,408 | scr 4 x 4,608
  const int tid = threadIdx.x;
  const int lane = tid & 63;
  const int l31 = lane & 31;
  const int hi  = lane >> 5;
  const int wn  = tid >> 6;

  // bid -> XCD-chunked bijective swizzle (3584 = 8*448)
  const int bid = blockIdx.x;
  const int wg  = (bid & 7) * 448 + (bid >> 3);
  const int coh = wg & 1;
  const int owc = (wg >> 1) & 1;
  const int rest = wg >> 2;
  const int ohp = rest % 28;
  const int b   = rest / 28;
  const int oh0 = ohp * 2;
  const int owbase = owc * 32;

  v16i acc[2];
  #pragma unroll
  for (int m = 0; m < 2; ++m)
    #pragma unroll
    for (int e = 0; e < 16; ++e) acc[m][e] = 0;

  // thread-constant bases; hot-loop offsets are compile-time immediates
  // af addr = lds + hi*2176 + (l31+kw)*16 + kcp*4352 + rr*544
  const char* abase = lds + hi * 2176 + l31 * 16;
  const v4i* wb = Wf + (coh * 4 + wn) * 64 + lane;  // ng = coh*4+wn
  const char* srcT = A8 + ((size_t)(b * HP + oh0) * HP + owbase) * 256;

  #pragma unroll
  for (int ph = 0; ph < 2; ++ph) {
    if (ph) __syncthreads();             // all waves done with phase-0 slab
    // ---- fill phase slab: linear i = (gr*4+rr)*34 + wwl ----
    for (int i = tid; i < 1088; i += 256) {
      int gr  = i / 136;                 // ci granule 0..7 (kcp*2+hi)
      int rem = i - gr * 136;
      int rr  = rem / 34;
      int wwl = rem - rr * 34;
      uint4 v = make_uint4(0u, 0u, 0u, 0u);
      if (owbase + wwl < HP)
        v = *(const uint4*)(srcT + ((size_t)rr * HP + wwl) * 256 +
                            ph * 128 + gr * 16);
      *(uint4*)(lds + i * 16) = v;
    }
    __syncthreads();

    #pragma unroll
    for (int kcp = 0; kcp < 4; ++kcp) {
      #pragma unroll
      for (int kw = 0; kw < 3; ++kw) {
        v4i af[4];
        #pragma unroll
        for (int rr = 0; rr < 4; ++rr)
          af[rr] = *(const v4i*)(abase + kcp * 4352 + rr * 544 + kw * 16);
        v4i bf[3];
        #pragma unroll
        for (int kh = 0; kh < 3; ++kh)
          bf[kh] = wb[((kh * 3 + kw) * 8 + ph * 4 + kcp) * 512];
        #pragma unroll
        for (int kh = 0; kh < 3; ++kh)
          #pragma unroll
          for (int ohl = 0; ohl < 2; ++ohl)
            acc[ohl] = __builtin_amdgcn_mfma_i32_32x32x32_i8(
                af[ohl + kh], bf[kh], acc[ohl], 0, 0, 0);
      }
    }
  }

  // ---- epilogue: per-wave transpose via dead slab, row stores ----
  __syncthreads();                   // slab dead for all waves
  char* scr = lds + wn * 4608;       // [co 32] stride 144B x 32 floats
  const int co0 = (coh * 4 + wn) * 32;

  #pragma unroll
  for (int ohl = 0; ohl < 2; ++ohl) {
    #pragma unroll
    for (int q = 0; q < 4; ++q) {
      float4 f;
      f.x = (float)acc[ohl][q * 4 + 0];
      f.y = (float)acc[ohl][q * 4 + 1];
      f.z = (float)acc[ohl][q * 4 + 2];
      f.w = (float)acc[ohl][q * 4 + 3];
      // m = q*8 + hi*4 + j -> byte q*32 + hi*16
      *(float4*)(scr + l31 * 144 + q * 32 + hi * 16) = f;
    }
    asm volatile("s_waitcnt lgkmcnt(0)" ::: "memory");
    __builtin_amdgcn_sched_barrier(0);
    #pragma unroll
    for (int t = 0; t < 4; ++t) {
      int idx = t * 64 + lane;       // 0..255 = co_l*8 + s
      int co_l = idx >> 3;
      int s = idx & 7;
      int ow = owbase + s * 4;
      if (ow + 3 < W_) {             // owc=1 drops s>=6 (garbage cols)
        float4 v = *(const float4*)(scr + co_l * 144 + s * 16);
        float* op = out + ((size_t)(b * COUT + co0 + co_l) * H_ + oh0 + ohl) * W_ + ow;
        *(float4*)op = v;
      }
    }
    asm volatile("s_waitcnt lgkmcnt(0)" ::: "memory");
    __builtin_amdgcn_sched_barrier(0);
  }
}

// ==================================================================
extern "C" void kernel_launch(void* const* d_in, const int* in_sizes, int n_in,
                              void* d_out, int out_size, void* d_ws, size_t ws_size,
                              hipStream_t stream) {
  const float* x     = (const float*)d_in[0];
  const float* alpha = (const float*)d_in[1];
  const float* wt    = (const float*)d_in[2];
  float* out = (float*)d_out;

  const size_t needA = (size_t)B_ * HP * HP * 256;   // 27,557,888 B
  char* A8 = (char*)d_ws;
  v4i* Wf  = (v4i*)(A8 + needA);

  pack_a8_kernel<<<dim3(15, 32), 256, 0, stream>>>(x, alpha, A8);
  pack_w8_kernel<<<144, 256, 0, stream>>>(wt, Wf);
  conv_mfma_kernel<<<dim3(B_ * 28 * 2 * 2), 256, 0, stream>>>(A8, Wf, out);
}

// Round 14
// 76.141 us; speedup vs baseline: 1.4386x; 1.4386x over previous
//
#include <hip/hip_runtime.h>
#include <cstdint>

#define B_   32
#define CIN  256
#define COUT 256
#define H_   56
#define W_   56
#define HP   58          // padded spatial dim (pad=1 each side)
#define HW   (H_ * W_)   // 3136

typedef int   v4i  __attribute__((ext_vector_type(4)));
typedef int   v8i  __attribute__((ext_vector_type(8)));
typedef float v16f __attribute__((ext_vector_type(16)));

// ==================================================================
// XNOR conv via MX-fp4 MFMA (9099 TOPS = 2.07x i8):
// a,w in {+1,-1} as fp4 e2m1 (+1=0x2, -1=0xA), zero-pad = 0x0 (exact).
// Unity scales: e8m0 byte 127 -> 2^0; scale word 0x7F7F7F7F (all bytes
// equal -> opsel-immune). Products +-1, sums <= 2304: exact in fp32.
// ==================================================================

// ---- pack_a4: NCHW fp32 -> padded NHWC fp4. A4[b][hh][ww][128B] ----
// nibble ci: byte ci>>1, low nibble first (same convention as Wf4).
__global__ __launch_bounds__(256) void pack_a4_kernel(
    const float* __restrict__ x, const float* __restrict__ alpha,
    char* __restrict__ A4) {
  const int w = threadIdx.x & 63;
  const int q = threadIdx.x >> 6;
  const int hh = blockIdx.x * 4 + q;
  const int b = blockIdx.y;
  if (hh >= HP) return;
  char* rowbase = A4 + (size_t)(b * HP + hh) * (HP * 128);
  const uint4 z = make_uint4(0u, 0u, 0u, 0u);
  if (hh == 0 || hh == HP - 1) {           // border row: all zeros
    for (int i = w; i < HP * 8; i += 64) *(uint4*)(rowbase + i * 16) = z;
    return;
  }
  const int h = hh - 1;
  if (w < W_) {
    char* dst = rowbase + (w + 1) * 128;
    const float* xp = x + (size_t)b * CIN * HW + h * W_ + w;
    #pragma unroll
    for (int cw = 0; cw < 8; ++cw) {       // 16B = 32 channels per iter
      uint32_t wd[4];
      #pragma unroll
      for (int u = 0; u < 4; ++u) {
        uint32_t word = 0;
        #pragma unroll
        for (int n = 0; n < 8; ++n) {
          int c = cw * 32 + u * 8 + n;
          float v = xp[(size_t)c * HW];
          word |= ((v > alpha[c]) ? 0x2u : 0xAu) << (n * 4);
        }
        wd[u] = word;
      }
      *(uint4*)(dst + cw * 16) = *(uint4*)wd;
    }
  } else if (w == 56 || w == 57) {         // border pixels ww=0 / ww=57
    char* dst = rowbase + ((w == 56) ? 0 : (HP - 1)) * 128;
    #pragma unroll
    for (int i = 0; i < 8; ++i) *(uint4*)(dst + i * 16) = z;
  }
}

// ---- pack_w4: W in B-fragment form for mfma 32x32x64 fp4 ----
// Wf4[((tap*4 + kc)*8 + ng)*64 + lane] (16B): co = ng*32 + (lane&31),
// k elem j=0..31: ci = kc*64 + (lane>>5)*32 + j; nibble j -> byte j>>1.
__global__ __launch_bounds__(256) void pack_w4_kernel(
    const float* __restrict__ wt, v4i* __restrict__ Wf) {
  int id = blockIdx.x * 256 + threadIdx.x;   // 18432 total
  int lane = id & 63;
  int ng = (id >> 6) & 7;
  int kc = (id >> 9) & 3;
  int tap = id >> 11;
  if (tap >= 9) return;
  int kh = tap / 3, kw = tap - kh * 3;
  int co = ng * 32 + (lane & 31);
  int cib = kc * 64 + (lane >> 5) * 32;
  uint32_t wd[4];
  #pragma unroll
  for (int u = 0; u < 4; ++u) {
    uint32_t word = 0;
    #pragma unroll
    for (int n = 0; n < 8; ++n) {
      int ci = cib + u * 8 + n;
      float v = wt[((size_t)(co * CIN + ci) * 3 + kh) * 3 + kw];
      word |= ((v > 0.0f) ? 0x2u : 0xAu) << (n * 4);
    }
    wd[u] = word;
  }
  Wf[id] = *(v4i*)wd;
}

// ---- conv_mfma v11: r12 structure, MX-fp4 K=64 -> 12 batches ----
// Block: 256 thr / 4 waves. Tile M128 (4 oh x 32 ow) x N128 (coh).
// Wave: M128 x N32; acc[4] v16f = 64 regs.
// Slab (full 256 ci, fp4): [gr8][rr6][ww34] x 16B = 26,112 B, ONE fill.
// Batch (kc 0..3, kw 0..2): 6 af b128 reads + 3 bf 16B loads + 12 MFMAs
// -- same per-batch resources as r12-i8 but HALF the batch count.
// fp4 payload = low 4 regs of the v8i operand (16B/lane = 32 nibbles),
// upper 4 ignored (zero-filled); cbsz=blgp=4 (e2m1); unity scales.
__global__ __launch_bounds__(256, 3) void conv_mfma_kernel(
    const char* __restrict__ A4, const v4i* __restrict__ Wf,
    float* __restrict__ out) {
  __shared__ alignas(16) char lds[26112];   // [gr8][rr6][ww34] x 16B
  const int tid = threadIdx.x;
  const int lane = tid & 63;
  const int l31 = lane & 31;
  const int hi  = lane >> 5;
  const int wn  = tid >> 6;

  // bid -> XCD-chunked bijective swizzle (1792 = 8*224)
  const int bid = blockIdx.x;
  const int wg  = (bid & 7) * 224 + (bid >> 3);
  const int coh = wg & 1;
  const int owc = (wg >> 1) & 1;
  const int rest = wg >> 2;
  const int ohq = rest % 14;
  const int b   = rest / 14;
  const int oh0 = ohq * 4;
  const int owbase = owc * 32;

  // ---- fill slab: linear i = (gr*6+rr)*34 + wwl ----
  {
    const char* srcT = A4 + ((size_t)(b * HP + oh0) * HP + owbase) * 128;
    for (int i = tid; i < 1632; i += 256) {
      int gr  = i / 204;                 // ci granule 0..7 (kc*2+hi)
      int rem = i - gr * 204;
      int rr  = rem / 34;
      int wwl = rem - rr * 34;
      uint4 v = make_uint4(0u, 0u, 0u, 0u);
      if (owbase + wwl < HP)
        v = *(const uint4*)(srcT + ((size_t)rr * HP + wwl) * 128 + gr * 16);
      *(uint4*)(lds + i * 16) = v;
    }
  }
  __syncthreads();

  v16f acc[4];
  #pragma unroll
  for (int m = 0; m < 4; ++m)
    #pragma unroll
    for (int e = 0; e < 16; ++e) acc[m][e] = 0.0f;

  // af addr = lds + (kc*2+hi)*3264 + rr*544 + (l31+kw)*16
  const char* abase = lds + hi * 3264 + l31 * 16;
  const v4i* wb = Wf + (coh * 4 + wn) * 64 + lane;  // ng = coh*4+wn
  const v4i zero4 = {0, 0, 0, 0};

  #pragma unroll
  for (int kc = 0; kc < 4; ++kc) {
    #pragma unroll
    for (int kw = 0; kw < 3; ++kw) {
      v4i af[6];
      #pragma unroll
      for (int rr = 0; rr < 6; ++rr)
        af[rr] = *(const v4i*)(abase + kc * 6528 + rr * 544 + kw * 16);
      v4i bf[3];
      #pragma unroll
      for (int kh = 0; kh < 3; ++kh)
        bf[kh] = wb[((kh * 3 + kw) * 4 + kc) * 512];
      #pragma unroll
      for (int kh = 0; kh < 3; ++kh) {
        v8i b8 = __builtin_shufflevector(bf[kh], zero4, 0, 1, 2, 3, 4, 5, 6, 7);
        #pragma unroll
        for (int ohl = 0; ohl < 4; ++ohl) {
          v8i a8 = __builtin_shufflevector(af[ohl + kh], zero4, 0, 1, 2, 3, 4, 5, 6, 7);
          acc[ohl] = __builtin_amdgcn_mfma_scale_f32_32x32x64_f8f6f4(
              a8, b8, acc[ohl], 4, 4,           // cbsz=4 (fp4), blgp=4 (fp4)
              0, 0x7F7F7F7F,                     // opsel_a, scale_a (unity)
              0, 0x7F7F7F7F);                    // opsel_b, scale_b (unity)
        }
      }
    }
  }

  // ---- epilogue: per-wave transpose via dead slab, row stores ----
  __syncthreads();                   // slab dead for all waves
  char* scr = lds + wn * 4608;       // [co 32] stride 144B x 32 floats
  const int co0 = (coh * 4 + wn) * 32;

  #pragma unroll
  for (int ohl = 0; ohl < 4; ++ohl) {
    #pragma unroll
    for (int q = 0; q < 4; ++q) {
      float4 f;
      f.x = acc[ohl][q * 4 + 0];
      f.y = acc[ohl][q * 4 + 1];
      f.z = acc[ohl][q * 4 + 2];
      f.w = acc[ohl][q * 4 + 3];
      // m = q*8 + hi*4 + j -> byte q*32 + hi*16
      *(float4*)(scr + l31 * 144 + q * 32 + hi * 16) = f;
    }
    asm volatile("s_waitcnt lgkmcnt(0)" ::: "memory");
    __builtin_amdgcn_sched_barrier(0);
    #pragma unroll
    for (int t = 0; t < 4; ++t) {
      int idx = t * 64 + lane;       // 0..255 = co_l*8 + s
      int co_l = idx >> 3;
      int s = idx & 7;
      int ow = owbase + s * 4;
      if (ow + 3 < W_) {             // owc=1 drops s>=6 (garbage cols)
        float4 v = *(const float4*)(scr + co_l * 144 + s * 16);
        float* op = out + ((size_t)(b * COUT + co0 + co_l) * H_ + oh0 + ohl) * W_ + ow;
        *(float4*)op = v;
      }
    }
    asm volatile("s_waitcnt lgkmcnt(0)" ::: "memory");
    __builtin_amdgcn_sched_barrier(0);
  }
}

// ==================================================================
extern "C" void kernel_launch(void* const* d_in, const int* in_sizes, int n_in,
                              void* d_out, int out_size, void* d_ws, size_t ws_size,
                              hipStream_t stream) {
  const float* x     = (const float*)d_in[0];
  const float* alpha = (const float*)d_in[1];
  const float* wt    = (const float*)d_in[2];
  float* out = (float*)d_out;

  const size_t needA = (size_t)B_ * HP * HP * 128;   // 13,778,944 B
  char* A4 = (char*)d_ws;
  v4i* Wf  = (v4i*)(A4 + needA);                     // 294,912 B

  pack_a4_kernel<<<dim3(15, 32), 256, 0, stream>>>(x, alpha, A4);
  pack_w4_kernel<<<72, 256, 0, stream>>>(wt, Wf);
  conv_mfma_kernel<<<dim3(B_ * 14 * 2 * 2), 256, 0, stream>>>(A4, Wf, out);
}